// Round 4
// baseline (368.696 us; speedup 1.0000x reference)
//
#include <hip/hip_runtime.h>

typedef __bf16 bf16x8 __attribute__((ext_vector_type(8)));
typedef float f32x4 __attribute__((ext_vector_type(4)));

__device__ __forceinline__ unsigned short f2b(float f) {
    unsigned int u = __float_as_uint(f);
    u = (u + 0x7fffu + ((u >> 16) & 1u)) >> 16;
    return (unsigned short)u;
}

// ---------------- fused fp32 -> bf16 convert for x + 4 weight matrices ----------------
__global__ __launch_bounds__(256) void cvt_all(
    const float* __restrict__ s0, unsigned short* __restrict__ d0,   // x      (786432 f4)
    const float* __restrict__ s1, unsigned short* __restrict__ d1,   // ipw    (442368 f4)
    const float* __restrict__ s2, unsigned short* __restrict__ d2,   // ow     (147456 f4)
    const float* __restrict__ s3, unsigned short* __restrict__ d3,   // fw1    (589824 f4)
    const float* __restrict__ s4, unsigned short* __restrict__ d4)   // fw2    (589824 f4)
{
    int i = blockIdx.x * 256 + threadIdx.x;
    const float* s; unsigned short* d; int j;
    if (i < 786432)       { s = s0; d = d0; j = i; }
    else if (i < 1228800) { s = s1; d = d1; j = i - 786432; }
    else if (i < 1376256) { s = s2; d = d2; j = i - 1228800; }
    else if (i < 1966080) { s = s3; d = d3; j = i - 1376256; }
    else                  { s = s4; d = d4; j = i - 1966080; }
    float4 v = ((const float4*)s)[j];
    ushort4 o;
    o.x = f2b(v.x); o.y = f2b(v.y); o.z = f2b(v.z); o.w = f2b(v.w);
    ((ushort4*)d)[j] = o;
}

__global__ __launch_bounds__(256) void zero_f32(float4* __restrict__ p, int n4) {
    int i = blockIdx.x * 256 + threadIdx.x;
    if (i < n4) p[i] = make_float4(0.f, 0.f, 0.f, 0.f);
}

// ---------------- NT GEMM: C = A[M,K] * B[N,K]^T + bias ----------------
// EPI 0: bias -> bf16 out; EPI 1: bias -> f32 out; EPI 2: bias+GELU(exact) -> bf16 out
// EPI 3: split-K (gridDim.z slices): bias at z==0, f32 atomicAdd out
#define GL16(g, s) __builtin_amdgcn_global_load_lds( \
    (const __attribute__((address_space(1))) unsigned int*)(g), \
    (__attribute__((address_space(3))) unsigned int*)(s), 16, 0, 0)

template<int EPI>
__global__ __launch_bounds__(256) void gemm_nt(
    const unsigned short* __restrict__ A,
    const unsigned short* __restrict__ B,
    const float* __restrict__ bias,
    float* __restrict__ Cf, unsigned short* __restrict__ Cb,
    int M, int N, int K)
{
    __shared__ __align__(16) unsigned short As[128 * 64];
    __shared__ __align__(16) unsigned short Bs[128 * 64];
    // bijective XCD swizzle of the (bx,by) tile id (nwg per z-slice is %8==0)
    const int nwg = gridDim.x * gridDim.y;
    const int lin = blockIdx.y * gridDim.x + blockIdx.x;
    const int qq = nwg >> 3;
    const int swz = (lin & 7) * qq + (lin >> 3);
    const int bx = swz % gridDim.x;
    const int by = swz / gridDim.x;

    const int tid = threadIdx.x;
    const int l = tid & 63;
    const int w = tid >> 6;
    const int wr = w >> 1, wc = w & 1;
    const long arow = (long)by * 128 + (tid >> 3);
    const long brow = (long)bx * 128 + (tid >> 3);
    const int kc = (tid & 7) * 8;
    const unsigned short* Ap = A + arow * K + kc;
    const unsigned short* Bp = B + brow * K + kc;

    const int kslice = K / gridDim.z;
    const int kbeg = blockIdx.z * kslice;
    const int kend = kbeg + kslice;

    f32x4 acc[4][4] = {};

    for (int k0 = kbeg; k0 < kend; k0 += 64) {
#pragma unroll
        for (int i = 0; i < 4; ++i) {
            GL16(Ap + k0 + (long)32 * i * K, As + i * 2048 + tid * 8);
            GL16(Bp + k0 + (long)32 * i * K, Bs + i * 2048 + tid * 8);
        }
        __syncthreads();
#pragma unroll
        for (int kk = 0; kk < 2; ++kk) {
            bf16x8 a[4], b[4];
#pragma unroll
            for (int m = 0; m < 4; ++m)
                a[m] = *(const bf16x8*)&As[(wr * 64 + m * 16 + (l & 15)) * 64 + kk * 32 + (l >> 4) * 8];
#pragma unroll
            for (int n = 0; n < 4; ++n)
                b[n] = *(const bf16x8*)&Bs[(wc * 64 + n * 16 + (l & 15)) * 64 + kk * 32 + (l >> 4) * 8];
#pragma unroll
            for (int m = 0; m < 4; ++m)
#pragma unroll
                for (int n = 0; n < 4; ++n)
                    acc[m][n] = __builtin_amdgcn_mfma_f32_16x16x32_bf16(a[m], b[n], acc[m][n], 0, 0, 0);
        }
        __syncthreads();
    }

    const int r0 = by * 128 + wr * 64 + ((l >> 4) << 2);
    const int c0 = bx * 128 + wc * 64 + (l & 15);
#pragma unroll
    for (int n = 0; n < 4; ++n) {
        const int col = c0 + n * 16;
        const float bv = bias[col];
#pragma unroll
        for (int m = 0; m < 4; ++m) {
#pragma unroll
            for (int r = 0; r < 4; ++r) {
                long row = r0 + m * 16 + r;
                float v = acc[m][n][r];
                if (EPI == 3) {
                    if (blockIdx.z == 0) v += bv;
                    unsafeAtomicAdd(&Cf[row * N + col], v);
                } else {
                    v += bv;
                    if (EPI == 2) v = 0.5f * v * (1.0f + erff(v * 0.70710678f));
                    if (EPI == 1) Cf[row * N + col] = v;
                    else          Cb[row * N + col] = f2b(v);
                }
            }
        }
    }
}

// ---------------- banded flash attention ----------------
// qkv: [4096][2304] bf16 (q|k|v sections of 768 each); ctx out: [4096][768] bf16
// grid: (L/64, H). Block: 256 thr (4 waves); wave w owns q rows w*16..w*16+15.
// 5 key-subtiles of 64 covering [q0-128, q0+191]. All LDS tiles 16B-chunk XOR-swizzled.
__global__ __launch_bounds__(256) void attn_local(
    const unsigned short* __restrict__ qkv,
    unsigned short* __restrict__ ctx,
    const int* __restrict__ winp)
{
    const int L = 4096;
    const int W = *winp;
    const int h = blockIdx.y;
    const int q0 = blockIdx.x * 64;
    const int tid = threadIdx.x;
    const int w = tid >> 6, l = tid & 63;
    __shared__ __align__(16) unsigned short Qs[64 * 64];
    __shared__ __align__(16) unsigned short Ks[64 * 64];
    __shared__ __align__(16) unsigned short Vs[64 * 64];
    __shared__ __align__(16) unsigned short Ps[64 * 64];

    // stage Q (rows q0..q0+63, head slice)
    {
        const int cg = tid & 7;
#pragma unroll
        for (int i = 0; i < 2; ++i) {
            int r = (tid >> 3) + 32 * i;
            uint4 v = *(const uint4*)&qkv[(long)(q0 + r) * 2304 + h * 64 + cg * 8];
            *(uint4*)&Qs[r * 64 + ((cg ^ (r & 7)) << 3)] = v;
        }
    }

    float mrow[4], lrow[4];
    f32x4 o[4] = {};
#pragma unroll
    for (int r = 0; r < 4; ++r) { mrow[r] = -1e30f; lrow[r] = 0.0f; }

    for (int st = 0; st < 5; ++st) {
        const int k0 = q0 - 128 + st * 64;
        __syncthreads();  // protect Ks/Vs from prior-iter readers
        // stage K and V^T (clamped rows; masked later)
        {
            const int cg = tid & 7;
#pragma unroll
            for (int i = 0; i < 2; ++i) {
                int r = (tid >> 3) + 32 * i;
                int kr = k0 + r;
                int krc = kr < 0 ? 0 : (kr >= L ? L - 1 : kr);
                uint4 kv = *(const uint4*)&qkv[(long)krc * 2304 + 768 + h * 64 + cg * 8];
                *(uint4*)&Ks[r * 64 + ((cg ^ (r & 7)) << 3)] = kv;
                uint4 vv = *(const uint4*)&qkv[(long)krc * 2304 + 1536 + h * 64 + cg * 8];
#pragma unroll
                for (int jj = 0; jj < 4; ++jj) {
                    unsigned int word = (jj == 0) ? vv.x : (jj == 1) ? vv.y : (jj == 2) ? vv.z : vv.w;
                    int d0 = cg * 8 + jj * 2;
                    int d1 = d0 + 1;
                    Vs[d0 * 64 + (((r >> 3) ^ (d0 & 7)) << 3) + (r & 7)] = (unsigned short)(word & 0xffffu);
                    Vs[d1 * 64 + (((r >> 3) ^ (d1 & 7)) << 3) + (r & 7)] = (unsigned short)(word >> 16);
                }
            }
        }
        __syncthreads();

        // S = Q K^T for this wave's 16 q rows x 64 keys
        f32x4 s[4] = {};
#pragma unroll
        for (int kk = 0; kk < 2; ++kk) {
            const int aro = w * 16 + (l & 15);
            bf16x8 aq = *(const bf16x8*)&Qs[aro * 64 + (((kk * 4 + (l >> 4)) ^ (aro & 7)) << 3)];
#pragma unroll
            for (int n = 0; n < 4; ++n) {
                const int bro = n * 16 + (l & 15);
                bf16x8 bk = *(const bf16x8*)&Ks[bro * 64 + (((kk * 4 + (l >> 4)) ^ (bro & 7)) << 3)];
                s[n] = __builtin_amdgcn_mfma_f32_16x16x32_bf16(aq, bk, s[n], 0, 0, 0);
            }
        }

        // mask + scale (C layout: col = l&15 -> key, row = (l>>4)*4+r -> q)
        const int qrow = q0 + w * 16 + ((l >> 4) << 2);
        const int kcol = k0 + (l & 15);
        float p[4][4];
#pragma unroll
        for (int n = 0; n < 4; ++n) {
#pragma unroll
            for (int r = 0; r < 4; ++r) {
                int key = kcol + n * 16;
                int q = qrow + r;
                int dd = q - key; if (dd < 0) dd = -dd;
                bool banned = (key < 0) || (key >= L) || (dd > W);
                p[n][r] = banned ? -1e30f : s[n][r] * 0.125f;
            }
        }
        // row max (reduce over low-4 lane bits = keys)
        float mx[4];
#pragma unroll
        for (int r = 0; r < 4; ++r)
            mx[r] = fmaxf(fmaxf(p[0][r], p[1][r]), fmaxf(p[2][r], p[3][r]));
#pragma unroll
        for (int off = 8; off >= 1; off >>= 1)
#pragma unroll
            for (int r = 0; r < 4; ++r)
                mx[r] = fmaxf(mx[r], __shfl_xor(mx[r], off));

        float sc[4], mn[4];
#pragma unroll
        for (int r = 0; r < 4; ++r) {
            mn[r] = fmaxf(mrow[r], mx[r]);
            sc[r] = __expf(mrow[r] - mn[r]);
            mrow[r] = mn[r];
        }
        float rs[4] = {0.f, 0.f, 0.f, 0.f};
#pragma unroll
        for (int n = 0; n < 4; ++n)
#pragma unroll
            for (int r = 0; r < 4; ++r) {
                float pv = __expf(p[n][r] - mn[r]);
                p[n][r] = pv;
                rs[r] += pv;
            }
#pragma unroll
        for (int off = 8; off >= 1; off >>= 1)
#pragma unroll
            for (int r = 0; r < 4; ++r)
                rs[r] += __shfl_xor(rs[r], off);
#pragma unroll
        for (int r = 0; r < 4; ++r)
            lrow[r] = lrow[r] * sc[r] + rs[r];
#pragma unroll
        for (int n = 0; n < 4; ++n)
#pragma unroll
            for (int r = 0; r < 4; ++r)
                o[n][r] *= sc[r];

        // write P (bf16) to wave-private LDS rows
#pragma unroll
        for (int n = 0; n < 4; ++n) {
            int col = n * 16 + (l & 15);
            int cb = col >> 3, ci = col & 7;
#pragma unroll
            for (int r = 0; r < 4; ++r) {
                int rp = w * 16 + ((l >> 4) << 2) + r;
                Ps[rp * 64 + ((cb ^ (rp & 7)) << 3) + ci] = f2b(p[n][r]);
            }
        }
        // O += P V  (A = P rows, B = V^T rows = dims)
#pragma unroll
        for (int kk = 0; kk < 2; ++kk) {
            const int aro = w * 16 + (l & 15);
            bf16x8 ap = *(const bf16x8*)&Ps[aro * 64 + (((kk * 4 + (l >> 4)) ^ (aro & 7)) << 3)];
#pragma unroll
            for (int n = 0; n < 4; ++n) {
                const int bro = n * 16 + (l & 15);
                bf16x8 bv = *(const bf16x8*)&Vs[bro * 64 + (((kk * 4 + (l >> 4)) ^ (bro & 7)) << 3)];
                o[n] = __builtin_amdgcn_mfma_f32_16x16x32_bf16(ap, bv, o[n], 0, 0, 0);
            }
        }
    }

    // normalize + write ctx
#pragma unroll
    for (int n = 0; n < 4; ++n) {
        int col = h * 64 + n * 16 + (l & 15);
#pragma unroll
        for (int r = 0; r < 4; ++r) {
            int q = q0 + w * 16 + ((l >> 4) << 2) + r;
            ctx[(long)q * 768 + col] = f2b(o[n][r] / lrow[r]);
        }
    }
}

// ---------------- residual add + LayerNorm ----------------
// out = LN(Ain + Bin) * w + b ; writes f32 (outf) and optional bf16 (outb)
__global__ __launch_bounds__(256) void ln_res(
    const float* __restrict__ Ain, const float* __restrict__ Bin,
    const float* __restrict__ w, const float* __restrict__ bb,
    float* __restrict__ outf, unsigned short* __restrict__ outb)
{
    const int D = 768;
    const int row = blockIdx.x;
    const int t = threadIdx.x;
    const float* pa = Ain + (long)row * D;
    const float* pb = Bin + (long)row * D;
    float x0 = pa[t] + pb[t];
    float x1 = pa[t + 256] + pb[t + 256];
    float x2 = pa[t + 512] + pb[t + 512];
    float s = x0 + x1 + x2;
    float ss = x0 * x0 + x1 * x1 + x2 * x2;
#pragma unroll
    for (int off = 32; off >= 1; off >>= 1) {
        s += __shfl_xor(s, off);
        ss += __shfl_xor(ss, off);
    }
    __shared__ float sm[8];
    if ((t & 63) == 0) { sm[t >> 6] = s; sm[(t >> 6) + 4] = ss; }
    __syncthreads();
    s = sm[0] + sm[1] + sm[2] + sm[3];
    ss = sm[4] + sm[5] + sm[6] + sm[7];
    float mu = s * (1.0f / 768.0f);
    float var = ss * (1.0f / 768.0f) - mu * mu;
    float rstd = rsqrtf(var + 1e-5f);
    float* po = outf + (long)row * D;
#pragma unroll
    for (int i = 0; i < 3; ++i) {
        int c = t + i * 256;
        float x = (i == 0) ? x0 : (i == 1) ? x1 : x2;
        float y = (x - mu) * rstd * w[c] + bb[c];
        po[c] = y;
        if (outb) outb[(long)row * D + c] = f2b(y);
    }
}

extern "C" void kernel_launch(void* const* d_in, const int* in_sizes, int n_in,
                              void* d_out, int out_size, void* d_ws, size_t ws_size,
                              hipStream_t stream) {
    const float* x   = (const float*)d_in[0];
    const float* ipw = (const float*)d_in[1];
    const float* ipb = (const float*)d_in[2];
    const float* ow  = (const float*)d_in[3];
    const float* ob  = (const float*)d_in[4];
    const float* l1w = (const float*)d_in[5];
    const float* l1b = (const float*)d_in[6];
    const float* l2w = (const float*)d_in[7];
    const float* l2b = (const float*)d_in[8];
    const float* fw1 = (const float*)d_in[9];
    const float* fb1 = (const float*)d_in[10];
    const float* fw2 = (const float*)d_in[11];
    const float* fb2 = (const float*)d_in[12];
    const int*   win = (const int*)d_in[13];

    const int L = 4096, D = 768, TD = 2304, FF = 3072;
    char* p = (char*)d_ws;
    unsigned short* xb   = (unsigned short*)p; p += (size_t)L * D * 2;
    unsigned short* wqkv = (unsigned short*)p; p += (size_t)TD * D * 2;
    unsigned short* wout = (unsigned short*)p; p += (size_t)D * D * 2;
    unsigned short* wf1  = (unsigned short*)p; p += (size_t)FF * D * 2;
    unsigned short* wf2  = (unsigned short*)p; p += (size_t)FF * D * 2;
    unsigned short* ctxb = (unsigned short*)p; p += (size_t)L * D * 2;   // also reused as hb
    float* tmpf          = (float*)p;          p += (size_t)L * D * 4;   // attn_out, then ff2_out
    float* hf            = (float*)p;          p += (size_t)L * D * 4;
    unsigned short* big  = (unsigned short*)p; p += (size_t)L * FF * 2;  // qkv bf16, then gelu-act
    unsigned short* qkvb = big;
    unsigned short* gb   = big;
    unsigned short* hb   = ctxb;  // ctx dead after out-proj; reuse for LN1 bf16 out

    // one fused convert for x + all weights (10.2M elems, 2555904 float4s)
    cvt_all<<<9984, 256, 0, stream>>>(x, xb, ipw, wqkv, ow, wout, fw1, wf1, fw2, wf2);

    // qkv = x @ in_proj_w^T + b  -> bf16 [L, 2304]
    gemm_nt<0><<<dim3(TD / 128, L / 128, 1), 256, 0, stream>>>(xb, wqkv, ipb, nullptr, qkvb, L, TD, D);
    // banded attention -> ctx bf16 [L, 768]
    attn_local<<<dim3(L / 64, 12), 256, 0, stream>>>(qkvb, ctxb, win);
    // attn_out = ctx @ out_w^T + b -> f32 (split-K=4, atomic)
    zero_f32<<<(L * D / 4 + 255) / 256, 256, 0, stream>>>((float4*)tmpf, L * D / 4);
    gemm_nt<3><<<dim3(D / 128, L / 128, 4), 256, 0, stream>>>(ctxb, wout, ob, tmpf, nullptr, L, D, D);
    // h = LN(x + attn_out) -> f32 + bf16
    ln_res<<<L, 256, 0, stream>>>(x, tmpf, l1w, l1b, hf, hb);
    // g = gelu(h @ ff_w1^T + b1) -> bf16 [L, 3072]
    gemm_nt<2><<<dim3(FF / 128, L / 128, 1), 256, 0, stream>>>(hb, wf1, fb1, nullptr, gb, L, FF, D);
    // ff = g @ ff_w2^T + b2 -> f32 (split-K=4, atomic)
    zero_f32<<<(L * D / 4 + 255) / 256, 256, 0, stream>>>((float4*)tmpf, L * D / 4);
    gemm_nt<3><<<dim3(D / 128, L / 128, 4), 256, 0, stream>>>(gb, wf2, fb2, tmpf, nullptr, L, D, FF);
    // out = LN(h + ff) -> f32
    ln_res<<<L, 256, 0, stream>>>(hf, tmpf, l2w, l2b, (float*)d_out, nullptr);
}

// Round 5
// 314.798 us; speedup vs baseline: 1.1712x; 1.1712x over previous
//
#include <hip/hip_runtime.h>

typedef __bf16 bf16x8 __attribute__((ext_vector_type(8)));
typedef float f32x4 __attribute__((ext_vector_type(4)));

__device__ __forceinline__ unsigned short f2b(float f) {
    unsigned int u = __float_as_uint(f);
    u = (u + 0x7fffu + ((u >> 16) & 1u)) >> 16;
    return (unsigned short)u;
}

// ---------------- fused fp32 -> bf16 convert for x + 4 weight matrices ----------------
__global__ __launch_bounds__(256) void cvt_all(
    const float* __restrict__ s0, unsigned short* __restrict__ d0,   // x      (786432 f4)
    const float* __restrict__ s1, unsigned short* __restrict__ d1,   // ipw    (442368 f4)
    const float* __restrict__ s2, unsigned short* __restrict__ d2,   // ow     (147456 f4)
    const float* __restrict__ s3, unsigned short* __restrict__ d3,   // fw1    (589824 f4)
    const float* __restrict__ s4, unsigned short* __restrict__ d4)   // fw2    (589824 f4)
{
    int i = blockIdx.x * 256 + threadIdx.x;
    const float* s; unsigned short* d; int j;
    if (i < 786432)       { s = s0; d = d0; j = i; }
    else if (i < 1228800) { s = s1; d = d1; j = i - 786432; }
    else if (i < 1376256) { s = s2; d = d2; j = i - 1228800; }
    else if (i < 1966080) { s = s3; d = d3; j = i - 1376256; }
    else                  { s = s4; d = d4; j = i - 1966080; }
    float4 v = ((const float4*)s)[j];
    ushort4 o;
    o.x = f2b(v.x); o.y = f2b(v.y); o.z = f2b(v.z); o.w = f2b(v.w);
    ((ushort4*)d)[j] = o;
}

#define GL16(g, s) __builtin_amdgcn_global_load_lds( \
    (const __attribute__((address_space(1))) unsigned int*)(g), \
    (__attribute__((address_space(3))) unsigned int*)(s), 16, 0, 0)

// ---------------- 256x256-tile NT GEMM: C = A[M,K] * B[N,K]^T ----------------
// 512 thr / 8 waves (2M x 4N), per-wave 128x64 out, BK=64, single-buffer LDS.
// LDS 16B-chunk XOR swizzle via pre-swizzled GLOBAL source (m173 pattern):
//   LDS[row][chunk] holds global chunk (chunk ^ (row&7)); reads apply same XOR.
// EPI 0: bias -> bf16; EPI 2: bias+GELU(exact) -> bf16; EPI 3: f32 partial slice (no bias)
template<int EPI>
__global__ __launch_bounds__(512) void gemm_nt_256(
    const unsigned short* __restrict__ A,
    const unsigned short* __restrict__ B,
    const float* __restrict__ bias,
    float* __restrict__ Cf, unsigned short* __restrict__ Cb,
    int M, int N, int K)
{
    __shared__ __align__(16) unsigned short As[256 * 64];
    __shared__ __align__(16) unsigned short Bs[256 * 64];
    // bijective XCD swizzle of (bx,by); all grids here have (gx*gy)%8==0
    const int nwg = gridDim.x * gridDim.y;
    const int lin = blockIdx.y * gridDim.x + blockIdx.x;
    const int qq = nwg >> 3;
    const int swz = (lin & 7) * qq + (lin >> 3);
    const int bx = swz % gridDim.x;
    const int by = swz / gridDim.x;

    const int tid = threadIdx.x;
    const int l = tid & 63;
    const int w = tid >> 6;
    const int wr = w >> 2, wc = w & 3;          // 2 x 4 wave grid
    const long arow = (long)by * 256 + (tid >> 3);
    const long brow = (long)bx * 256 + (tid >> 3);
    // pre-swizzled source chunk: chunk ^= (row&7); row&7 == (tid>>3)&7 here
    const int kc = (((tid & 7) ^ ((tid >> 3) & 7)) << 3);
    const unsigned short* Ap = A + arow * K + kc;
    const unsigned short* Bp = B + brow * K + kc;

    const int kslice = K / gridDim.z;
    const int kbeg = blockIdx.z * kslice;
    const int kend = kbeg + kslice;

    f32x4 acc[8][4] = {};

    for (int k0 = kbeg; k0 < kend; k0 += 64) {
#pragma unroll
        for (int i = 0; i < 4; ++i) {
            GL16(Ap + k0 + (long)64 * i * K, As + i * 4096 + tid * 8);
            GL16(Bp + k0 + (long)64 * i * K, Bs + i * 4096 + tid * 8);
        }
        __syncthreads();
#pragma unroll
        for (int kk = 0; kk < 2; ++kk) {
            bf16x8 b[4];
#pragma unroll
            for (int n = 0; n < 4; ++n) {
                const int row = wc * 64 + n * 16 + (l & 15);
                const int ch = (kk * 4 + (l >> 4)) ^ (row & 7);
                b[n] = *(const bf16x8*)&Bs[row * 64 + (ch << 3)];
            }
#pragma unroll
            for (int m = 0; m < 8; ++m) {
                const int row = wr * 128 + m * 16 + (l & 15);
                const int ch = (kk * 4 + (l >> 4)) ^ (row & 7);
                bf16x8 a = *(const bf16x8*)&As[row * 64 + (ch << 3)];
#pragma unroll
                for (int n = 0; n < 4; ++n)
                    acc[m][n] = __builtin_amdgcn_mfma_f32_16x16x32_bf16(a, b[n], acc[m][n], 0, 0, 0);
            }
        }
        __syncthreads();
    }

    const int r0 = by * 256 + wr * 128 + ((l >> 4) << 2);
    const int c0 = bx * 256 + wc * 64 + (l & 15);
#pragma unroll
    for (int n = 0; n < 4; ++n) {
        const int col = c0 + n * 16;
        const float bv = (EPI == 3) ? 0.0f : bias[col];
#pragma unroll
        for (int m = 0; m < 8; ++m) {
#pragma unroll
            for (int r = 0; r < 4; ++r) {
                long row = r0 + m * 16 + r;
                float v = acc[m][n][r];
                if (EPI == 3) {
                    Cf[(long)blockIdx.z * M * N + row * N + col] = v;
                } else {
                    v += bv;
                    if (EPI == 2) v = 0.5f * v * (1.0f + erff(v * 0.70710678f));
                    Cb[row * N + col] = f2b(v);
                }
            }
        }
    }
}

// ---------------- 128x128-tile NT GEMM (for skinny out-proj) ----------------
// EPI 3: f32 partial slice per z (no bias, no atomics)
template<int EPI>
__global__ __launch_bounds__(256) void gemm_nt(
    const unsigned short* __restrict__ A,
    const unsigned short* __restrict__ B,
    const float* __restrict__ bias,
    float* __restrict__ Cf, unsigned short* __restrict__ Cb,
    int M, int N, int K)
{
    __shared__ __align__(16) unsigned short As[128 * 64];
    __shared__ __align__(16) unsigned short Bs[128 * 64];
    const int nwg = gridDim.x * gridDim.y;
    const int lin = blockIdx.y * gridDim.x + blockIdx.x;
    const int qq = nwg >> 3;
    const int swz = (lin & 7) * qq + (lin >> 3);
    const int bx = swz % gridDim.x;
    const int by = swz / gridDim.x;

    const int tid = threadIdx.x;
    const int l = tid & 63;
    const int w = tid >> 6;
    const int wr = w >> 1, wc = w & 1;
    const long arow = (long)by * 128 + (tid >> 3);
    const long brow = (long)bx * 128 + (tid >> 3);
    const int kc = (tid & 7) * 8;
    const unsigned short* Ap = A + arow * K + kc;
    const unsigned short* Bp = B + brow * K + kc;

    const int kslice = K / gridDim.z;
    const int kbeg = blockIdx.z * kslice;
    const int kend = kbeg + kslice;

    f32x4 acc[4][4] = {};

    for (int k0 = kbeg; k0 < kend; k0 += 64) {
#pragma unroll
        for (int i = 0; i < 4; ++i) {
            GL16(Ap + k0 + (long)32 * i * K, As + i * 2048 + tid * 8);
            GL16(Bp + k0 + (long)32 * i * K, Bs + i * 2048 + tid * 8);
        }
        __syncthreads();
#pragma unroll
        for (int kk = 0; kk < 2; ++kk) {
            bf16x8 a[4], b[4];
#pragma unroll
            for (int m = 0; m < 4; ++m)
                a[m] = *(const bf16x8*)&As[(wr * 64 + m * 16 + (l & 15)) * 64 + kk * 32 + (l >> 4) * 8];
#pragma unroll
            for (int n = 0; n < 4; ++n)
                b[n] = *(const bf16x8*)&Bs[(wc * 64 + n * 16 + (l & 15)) * 64 + kk * 32 + (l >> 4) * 8];
#pragma unroll
            for (int m = 0; m < 4; ++m)
#pragma unroll
                for (int n = 0; n < 4; ++n)
                    acc[m][n] = __builtin_amdgcn_mfma_f32_16x16x32_bf16(a[m], b[n], acc[m][n], 0, 0, 0);
        }
        __syncthreads();
    }

    const int r0 = by * 128 + wr * 64 + ((l >> 4) << 2);
    const int c0 = bx * 128 + wc * 64 + (l & 15);
#pragma unroll
    for (int n = 0; n < 4; ++n) {
        const int col = c0 + n * 16;
        const float bv = (EPI == 3) ? 0.0f : bias[col];
#pragma unroll
        for (int m = 0; m < 4; ++m) {
#pragma unroll
            for (int r = 0; r < 4; ++r) {
                long row = r0 + m * 16 + r;
                float v = acc[m][n][r];
                if (EPI == 3) {
                    Cf[(long)blockIdx.z * M * N + row * N + col] = v;
                } else {
                    v += bv;
                    if (EPI == 2) v = 0.5f * v * (1.0f + erff(v * 0.70710678f));
                    if (EPI == 1) Cf[row * N + col] = v;
                    else          Cb[row * N + col] = f2b(v);
                }
            }
        }
    }
}

// ---------------- banded flash attention (unchanged) ----------------
__global__ __launch_bounds__(256) void attn_local(
    const unsigned short* __restrict__ qkv,
    unsigned short* __restrict__ ctx,
    const int* __restrict__ winp)
{
    const int L = 4096;
    const int W = *winp;
    const int h = blockIdx.y;
    const int q0 = blockIdx.x * 64;
    const int tid = threadIdx.x;
    const int w = tid >> 6, l = tid & 63;
    __shared__ __align__(16) unsigned short Qs[64 * 64];
    __shared__ __align__(16) unsigned short Ks[64 * 64];
    __shared__ __align__(16) unsigned short Vs[64 * 64];
    __shared__ __align__(16) unsigned short Ps[64 * 64];

    {
        const int cg = tid & 7;
#pragma unroll
        for (int i = 0; i < 2; ++i) {
            int r = (tid >> 3) + 32 * i;
            uint4 v = *(const uint4*)&qkv[(long)(q0 + r) * 2304 + h * 64 + cg * 8];
            *(uint4*)&Qs[r * 64 + ((cg ^ (r & 7)) << 3)] = v;
        }
    }

    float mrow[4], lrow[4];
    f32x4 o[4] = {};
#pragma unroll
    for (int r = 0; r < 4; ++r) { mrow[r] = -1e30f; lrow[r] = 0.0f; }

    for (int st = 0; st < 5; ++st) {
        const int k0 = q0 - 128 + st * 64;
        __syncthreads();
        {
            const int cg = tid & 7;
#pragma unroll
            for (int i = 0; i < 2; ++i) {
                int r = (tid >> 3) + 32 * i;
                int kr = k0 + r;
                int krc = kr < 0 ? 0 : (kr >= L ? L - 1 : kr);
                uint4 kv = *(const uint4*)&qkv[(long)krc * 2304 + 768 + h * 64 + cg * 8];
                *(uint4*)&Ks[r * 64 + ((cg ^ (r & 7)) << 3)] = kv;
                uint4 vv = *(const uint4*)&qkv[(long)krc * 2304 + 1536 + h * 64 + cg * 8];
#pragma unroll
                for (int jj = 0; jj < 4; ++jj) {
                    unsigned int word = (jj == 0) ? vv.x : (jj == 1) ? vv.y : (jj == 2) ? vv.z : vv.w;
                    int d0 = cg * 8 + jj * 2;
                    int d1 = d0 + 1;
                    Vs[d0 * 64 + (((r >> 3) ^ (d0 & 7)) << 3) + (r & 7)] = (unsigned short)(word & 0xffffu);
                    Vs[d1 * 64 + (((r >> 3) ^ (d1 & 7)) << 3) + (r & 7)] = (unsigned short)(word >> 16);
                }
            }
        }
        __syncthreads();

        f32x4 s[4] = {};
#pragma unroll
        for (int kk = 0; kk < 2; ++kk) {
            const int aro = w * 16 + (l & 15);
            bf16x8 aq = *(const bf16x8*)&Qs[aro * 64 + (((kk * 4 + (l >> 4)) ^ (aro & 7)) << 3)];
#pragma unroll
            for (int n = 0; n < 4; ++n) {
                const int bro = n * 16 + (l & 15);
                bf16x8 bk = *(const bf16x8*)&Ks[bro * 64 + (((kk * 4 + (l >> 4)) ^ (bro & 7)) << 3)];
                s[n] = __builtin_amdgcn_mfma_f32_16x16x32_bf16(aq, bk, s[n], 0, 0, 0);
            }
        }

        const int qrow = q0 + w * 16 + ((l >> 4) << 2);
        const int kcol = k0 + (l & 15);
        float p[4][4];
#pragma unroll
        for (int n = 0; n < 4; ++n) {
#pragma unroll
            for (int r = 0; r < 4; ++r) {
                int key = kcol + n * 16;
                int q = qrow + r;
                int dd = q - key; if (dd < 0) dd = -dd;
                bool banned = (key < 0) || (key >= L) || (dd > W);
                p[n][r] = banned ? -1e30f : s[n][r] * 0.125f;
            }
        }
        float mx[4];
#pragma unroll
        for (int r = 0; r < 4; ++r)
            mx[r] = fmaxf(fmaxf(p[0][r], p[1][r]), fmaxf(p[2][r], p[3][r]));
#pragma unroll
        for (int off = 8; off >= 1; off >>= 1)
#pragma unroll
            for (int r = 0; r < 4; ++r)
                mx[r] = fmaxf(mx[r], __shfl_xor(mx[r], off));

        float sc[4], mn[4];
#pragma unroll
        for (int r = 0; r < 4; ++r) {
            mn[r] = fmaxf(mrow[r], mx[r]);
            sc[r] = __expf(mrow[r] - mn[r]);
            mrow[r] = mn[r];
        }
        float rs[4] = {0.f, 0.f, 0.f, 0.f};
#pragma unroll
        for (int n = 0; n < 4; ++n)
#pragma unroll
            for (int r = 0; r < 4; ++r) {
                float pv = __expf(p[n][r] - mn[r]);
                p[n][r] = pv;
                rs[r] += pv;
            }
#pragma unroll
        for (int off = 8; off >= 1; off >>= 1)
#pragma unroll
            for (int r = 0; r < 4; ++r)
                rs[r] += __shfl_xor(rs[r], off);
#pragma unroll
        for (int r = 0; r < 4; ++r)
            lrow[r] = lrow[r] * sc[r] + rs[r];
#pragma unroll
        for (int n = 0; n < 4; ++n)
#pragma unroll
            for (int r = 0; r < 4; ++r)
                o[n][r] *= sc[r];

#pragma unroll
        for (int n = 0; n < 4; ++n) {
            int col = n * 16 + (l & 15);
            int cb = col >> 3, ci = col & 7;
#pragma unroll
            for (int r = 0; r < 4; ++r) {
                int rp = w * 16 + ((l >> 4) << 2) + r;
                Ps[rp * 64 + ((cb ^ (rp & 7)) << 3) + ci] = f2b(p[n][r]);
            }
        }
#pragma unroll
        for (int kk = 0; kk < 2; ++kk) {
            const int aro = w * 16 + (l & 15);
            bf16x8 ap = *(const bf16x8*)&Ps[aro * 64 + (((kk * 4 + (l >> 4)) ^ (aro & 7)) << 3)];
#pragma unroll
            for (int n = 0; n < 4; ++n) {
                const int bro = n * 16 + (l & 15);
                bf16x8 bv = *(const bf16x8*)&Vs[bro * 64 + (((kk * 4 + (l >> 4)) ^ (bro & 7)) << 3)];
                o[n] = __builtin_amdgcn_mfma_f32_16x16x32_bf16(ap, bv, o[n], 0, 0, 0);
            }
        }
    }

#pragma unroll
    for (int n = 0; n < 4; ++n) {
        int col = h * 64 + n * 16 + (l & 15);
#pragma unroll
        for (int r = 0; r < 4; ++r) {
            int q = q0 + w * 16 + ((l >> 4) << 2) + r;
            ctx[(long)q * 768 + col] = f2b(o[n][r] / lrow[r]);
        }
    }
}

// ---------------- residual + 2-slice split-K reduce + bias + LayerNorm ----------------
// out = LN(A + (parts0 + parts1 + pbias)) * w + b ; f32 out + optional bf16 out
__global__ __launch_bounds__(256) void ln_res2(
    const float* __restrict__ A, const float* __restrict__ parts,
    const float* __restrict__ pbias,
    const float* __restrict__ w, const float* __restrict__ bb,
    float* __restrict__ outf, unsigned short* __restrict__ outb)
{
    const int D = 768;
    const long PS = (long)4096 * 768;
    const int row = blockIdx.x;
    const int t = threadIdx.x;
    const long base = (long)row * D;
    float xs[3];
#pragma unroll
    for (int i = 0; i < 3; ++i) {
        int c = t + i * 256;
        xs[i] = A[base + c] + pbias[c] + parts[base + c] + parts[PS + base + c];
    }
    float s = xs[0] + xs[1] + xs[2];
    float ss = xs[0] * xs[0] + xs[1] * xs[1] + xs[2] * xs[2];
#pragma unroll
    for (int off = 32; off >= 1; off >>= 1) {
        s += __shfl_xor(s, off);
        ss += __shfl_xor(ss, off);
    }
    __shared__ float sm[8];
    if ((t & 63) == 0) { sm[t >> 6] = s; sm[(t >> 6) + 4] = ss; }
    __syncthreads();
    s = sm[0] + sm[1] + sm[2] + sm[3];
    ss = sm[4] + sm[5] + sm[6] + sm[7];
    float mu = s * (1.0f / 768.0f);
    float var = ss * (1.0f / 768.0f) - mu * mu;
    float rstd = rsqrtf(var + 1e-5f);
#pragma unroll
    for (int i = 0; i < 3; ++i) {
        int c = t + i * 256;
        float y = (xs[i] - mu) * rstd * w[c] + bb[c];
        outf[base + c] = y;
        if (outb) outb[base + c] = f2b(y);
    }
}

extern "C" void kernel_launch(void* const* d_in, const int* in_sizes, int n_in,
                              void* d_out, int out_size, void* d_ws, size_t ws_size,
                              hipStream_t stream) {
    const float* x   = (const float*)d_in[0];
    const float* ipw = (const float*)d_in[1];
    const float* ipb = (const float*)d_in[2];
    const float* ow  = (const float*)d_in[3];
    const float* ob  = (const float*)d_in[4];
    const float* l1w = (const float*)d_in[5];
    const float* l1b = (const float*)d_in[6];
    const float* l2w = (const float*)d_in[7];
    const float* l2b = (const float*)d_in[8];
    const float* fw1 = (const float*)d_in[9];
    const float* fb1 = (const float*)d_in[10];
    const float* fw2 = (const float*)d_in[11];
    const float* fb2 = (const float*)d_in[12];
    const int*   win = (const int*)d_in[13];

    const int L = 4096, D = 768, TD = 2304, FF = 3072;
    char* p = (char*)d_ws;
    unsigned short* xb   = (unsigned short*)p; p += (size_t)L * D * 2;
    unsigned short* wqkv = (unsigned short*)p; p += (size_t)TD * D * 2;
    unsigned short* wout = (unsigned short*)p; p += (size_t)D * D * 2;
    unsigned short* wf1  = (unsigned short*)p; p += (size_t)FF * D * 2;
    unsigned short* wf2  = (unsigned short*)p; p += (size_t)FF * D * 2;
    unsigned short* ctxb = (unsigned short*)p; p += (size_t)L * D * 2;   // ctx, then LN1 bf16 out
    float* parts         = (float*)p;          p += (size_t)2 * L * D * 4; // 2 split-K slices
    float* hf            = (float*)p;          p += (size_t)L * D * 4;
    unsigned short* big  = (unsigned short*)p; p += (size_t)L * FF * 2;  // qkv bf16, then gelu-act
    unsigned short* qkvb = big;
    unsigned short* gb   = big;
    unsigned short* hb   = ctxb;

    // fused f32->bf16 converts (2555904 float4s)
    cvt_all<<<9984, 256, 0, stream>>>(x, xb, ipw, wqkv, ow, wout, fw1, wf1, fw2, wf2);

    // qkv = x @ in_proj_w^T + b -> bf16 [L, 2304]   (256^2 tile, 9x16 grid)
    gemm_nt_256<0><<<dim3(TD / 256, L / 256, 1), 512, 0, stream>>>(xb, wqkv, ipb, nullptr, qkvb, L, TD, D);
    // banded attention -> ctx bf16 [L, 768]
    attn_local<<<dim3(L / 64, 12), 256, 0, stream>>>(qkvb, ctxb, win);
    // attn_out partials: ctx @ out_w^T (128^2 tile, split-K=2, no bias/atomics)
    gemm_nt<3><<<dim3(D / 128, L / 128, 2), 256, 0, stream>>>(ctxb, wout, nullptr, parts, nullptr, L, D, D);
    // h = LN(x + partials + ob) -> f32 + bf16
    ln_res2<<<L, 256, 0, stream>>>(x, parts, ob, l1w, l1b, hf, hb);
    // g = gelu(h @ ff_w1^T + b1) -> bf16 [L, 3072]  (256^2 tile, 12x16 grid)
    gemm_nt_256<2><<<dim3(FF / 256, L / 256, 1), 512, 0, stream>>>(hb, wf1, fb1, nullptr, gb, L, FF, D);
    // ff partials: g @ ff_w2^T (256^2 tile, split-K=2)
    gemm_nt_256<3><<<dim3(D / 256, L / 256, 2), 512, 0, stream>>>(gb, wf2, nullptr, parts, nullptr, L, D, FF);
    // out = LN(h + partials + fb2) -> f32
    ln_res2<<<L, 256, 0, stream>>>(hf, parts, fb2, l2w, l2b, (float*)d_out, nullptr);
}

// Round 6
// 275.336 us; speedup vs baseline: 1.3391x; 1.1433x over previous
//
#include <hip/hip_runtime.h>

typedef __bf16 bf16x8 __attribute__((ext_vector_type(8)));
typedef float f32x4 __attribute__((ext_vector_type(4)));

__device__ __forceinline__ unsigned short f2b(float f) {
    unsigned int u = __float_as_uint(f);
    u = (u + 0x7fffu + ((u >> 16) & 1u)) >> 16;
    return (unsigned short)u;
}

// ---------------- fused fp32 -> bf16 convert for x + 4 weight matrices ----------------
__global__ __launch_bounds__(256) void cvt_all(
    const float* __restrict__ s0, unsigned short* __restrict__ d0,   // x      (786432 f4)
    const float* __restrict__ s1, unsigned short* __restrict__ d1,   // ipw    (442368 f4)
    const float* __restrict__ s2, unsigned short* __restrict__ d2,   // ow     (147456 f4)
    const float* __restrict__ s3, unsigned short* __restrict__ d3,   // fw1    (589824 f4)
    const float* __restrict__ s4, unsigned short* __restrict__ d4)   // fw2    (589824 f4)
{
    int i = blockIdx.x * 256 + threadIdx.x;
    const float* s; unsigned short* d; int j;
    if (i < 786432)       { s = s0; d = d0; j = i; }
    else if (i < 1228800) { s = s1; d = d1; j = i - 786432; }
    else if (i < 1376256) { s = s2; d = d2; j = i - 1228800; }
    else if (i < 1966080) { s = s3; d = d3; j = i - 1376256; }
    else                  { s = s4; d = d4; j = i - 1966080; }
    float4 v = ((const float4*)s)[j];
    ushort4 o;
    o.x = f2b(v.x); o.y = f2b(v.y); o.z = f2b(v.z); o.w = f2b(v.w);
    ((ushort4*)d)[j] = o;
}

#define GL16(g, s) __builtin_amdgcn_global_load_lds( \
    (const __attribute__((address_space(1))) unsigned int*)(g), \
    (__attribute__((address_space(3))) unsigned int*)(s), 16, 0, 0)

// ---------------- 2-phase pipelined 128x128 NT GEMM: C = A[M,K] * B[N,K]^T ----------------
// Double-buffered LDS (64 KB). Per iter: issue stage(next buf) -> compute(cur buf)
// -> ONE __syncthreads() (its vmcnt(0) drain lands a full compute-phase after issue).
// LDS 16B-chunk XOR swizzle via pre-swizzled GLOBAL source; reads apply same XOR.
// EPI 0: bias -> bf16; EPI 1: bias -> f32; EPI 2: bias+GELU(exact) -> bf16;
// EPI 3: f32 partial slice per z (no bias; reduced later in ln_res2)
template<int EPI>
__global__ __launch_bounds__(256) void gemm_nt_p(
    const unsigned short* __restrict__ A,
    const unsigned short* __restrict__ B,
    const float* __restrict__ bias,
    float* __restrict__ Cf, unsigned short* __restrict__ Cb,
    int M, int N, int K)
{
    __shared__ __align__(16) unsigned short As[2][128 * 64];
    __shared__ __align__(16) unsigned short Bs[2][128 * 64];
    // bijective XCD swizzle of (bx,by); all grids here have (gx*gy)%8==0
    const int nwg = gridDim.x * gridDim.y;
    const int lin = blockIdx.y * gridDim.x + blockIdx.x;
    const int qq = nwg >> 3;
    const int swz = (lin & 7) * qq + (lin >> 3);
    const int bx = swz % gridDim.x;
    const int by = swz / gridDim.x;

    const int tid = threadIdx.x;
    const int l = tid & 63;
    const int w = tid >> 6;
    const int wr = w >> 1, wc = w & 1;
    const long arow = (long)by * 128 + (tid >> 3);
    const long brow = (long)bx * 128 + (tid >> 3);
    // pre-swizzled source chunk: chunk ^= (row&7); LDS row here is tid>>3 (+32i, 0 mod 8)
    const int kc = (((tid & 7) ^ ((tid >> 3) & 7)) << 3);
    const unsigned short* Ap = A + arow * K + kc;
    const unsigned short* Bp = B + brow * K + kc;

    const int kslice = K / gridDim.z;
    const int kbeg = blockIdx.z * kslice;
    const int nt = kslice >> 6;

    f32x4 acc[4][4] = {};

    // prologue: stage tile 0 into buf 0
#pragma unroll
    for (int i = 0; i < 4; ++i) {
        GL16(Ap + kbeg + (long)32 * i * K, &As[0][i * 2048 + tid * 8]);
        GL16(Bp + kbeg + (long)32 * i * K, &Bs[0][i * 2048 + tid * 8]);
    }
    __syncthreads();

    int cur = 0;
    for (int t = 0; t < nt; ++t) {
        if (t + 1 < nt) {
            const long k0 = kbeg + (long)(t + 1) * 64;
#pragma unroll
            for (int i = 0; i < 4; ++i) {
                GL16(Ap + k0 + (long)32 * i * K, &As[cur ^ 1][i * 2048 + tid * 8]);
                GL16(Bp + k0 + (long)32 * i * K, &Bs[cur ^ 1][i * 2048 + tid * 8]);
            }
        }
#pragma unroll
        for (int kk = 0; kk < 2; ++kk) {
            bf16x8 a[4], b[4];
#pragma unroll
            for (int m = 0; m < 4; ++m) {
                const int row = wr * 64 + m * 16 + (l & 15);
                const int ch = (kk * 4 + (l >> 4)) ^ (row & 7);
                a[m] = *(const bf16x8*)&As[cur][row * 64 + (ch << 3)];
            }
#pragma unroll
            for (int n = 0; n < 4; ++n) {
                const int row = wc * 64 + n * 16 + (l & 15);
                const int ch = (kk * 4 + (l >> 4)) ^ (row & 7);
                b[n] = *(const bf16x8*)&Bs[cur][row * 64 + (ch << 3)];
            }
#pragma unroll
            for (int m = 0; m < 4; ++m)
#pragma unroll
                for (int n = 0; n < 4; ++n)
                    acc[m][n] = __builtin_amdgcn_mfma_f32_16x16x32_bf16(a[m], b[n], acc[m][n], 0, 0, 0);
        }
        __syncthreads();   // drains vmcnt(0): stage issued BEFORE compute -> latency hidden
        cur ^= 1;
    }

    const int r0 = by * 128 + wr * 64 + ((l >> 4) << 2);
    const int c0 = bx * 128 + wc * 64 + (l & 15);
#pragma unroll
    for (int n = 0; n < 4; ++n) {
        const int col = c0 + n * 16;
        const float bv = (EPI == 3) ? 0.0f : bias[col];
#pragma unroll
        for (int m = 0; m < 4; ++m) {
#pragma unroll
            for (int r = 0; r < 4; ++r) {
                long row = r0 + m * 16 + r;
                float v = acc[m][n][r];
                if (EPI == 3) {
                    Cf[(long)blockIdx.z * M * N + row * N + col] = v;
                } else {
                    v += bv;
                    if (EPI == 2) v = 0.5f * v * (1.0f + erff(v * 0.70710678f));
                    if (EPI == 1) Cf[row * N + col] = v;
                    else          Cb[row * N + col] = f2b(v);
                }
            }
        }
    }
}

// ---------------- banded flash attention (unchanged) ----------------
__global__ __launch_bounds__(256) void attn_local(
    const unsigned short* __restrict__ qkv,
    unsigned short* __restrict__ ctx,
    const int* __restrict__ winp)
{
    const int L = 4096;
    const int W = *winp;
    const int h = blockIdx.y;
    const int q0 = blockIdx.x * 64;
    const int tid = threadIdx.x;
    const int w = tid >> 6, l = tid & 63;
    __shared__ __align__(16) unsigned short Qs[64 * 64];
    __shared__ __align__(16) unsigned short Ks[64 * 64];
    __shared__ __align__(16) unsigned short Vs[64 * 64];
    __shared__ __align__(16) unsigned short Ps[64 * 64];

    {
        const int cg = tid & 7;
#pragma unroll
        for (int i = 0; i < 2; ++i) {
            int r = (tid >> 3) + 32 * i;
            uint4 v = *(const uint4*)&qkv[(long)(q0 + r) * 2304 + h * 64 + cg * 8];
            *(uint4*)&Qs[r * 64 + ((cg ^ (r & 7)) << 3)] = v;
        }
    }

    float mrow[4], lrow[4];
    f32x4 o[4] = {};
#pragma unroll
    for (int r = 0; r < 4; ++r) { mrow[r] = -1e30f; lrow[r] = 0.0f; }

    for (int st = 0; st < 5; ++st) {
        const int k0 = q0 - 128 + st * 64;
        __syncthreads();
        {
            const int cg = tid & 7;
#pragma unroll
            for (int i = 0; i < 2; ++i) {
                int r = (tid >> 3) + 32 * i;
                int kr = k0 + r;
                int krc = kr < 0 ? 0 : (kr >= L ? L - 1 : kr);
                uint4 kv = *(const uint4*)&qkv[(long)krc * 2304 + 768 + h * 64 + cg * 8];
                *(uint4*)&Ks[r * 64 + ((cg ^ (r & 7)) << 3)] = kv;
                uint4 vv = *(const uint4*)&qkv[(long)krc * 2304 + 1536 + h * 64 + cg * 8];
#pragma unroll
                for (int jj = 0; jj < 4; ++jj) {
                    unsigned int word = (jj == 0) ? vv.x : (jj == 1) ? vv.y : (jj == 2) ? vv.z : vv.w;
                    int d0 = cg * 8 + jj * 2;
                    int d1 = d0 + 1;
                    Vs[d0 * 64 + (((r >> 3) ^ (d0 & 7)) << 3) + (r & 7)] = (unsigned short)(word & 0xffffu);
                    Vs[d1 * 64 + (((r >> 3) ^ (d1 & 7)) << 3) + (r & 7)] = (unsigned short)(word >> 16);
                }
            }
        }
        __syncthreads();

        f32x4 s[4] = {};
#pragma unroll
        for (int kk = 0; kk < 2; ++kk) {
            const int aro = w * 16 + (l & 15);
            bf16x8 aq = *(const bf16x8*)&Qs[aro * 64 + (((kk * 4 + (l >> 4)) ^ (aro & 7)) << 3)];
#pragma unroll
            for (int n = 0; n < 4; ++n) {
                const int bro = n * 16 + (l & 15);
                bf16x8 bk = *(const bf16x8*)&Ks[bro * 64 + (((kk * 4 + (l >> 4)) ^ (bro & 7)) << 3)];
                s[n] = __builtin_amdgcn_mfma_f32_16x16x32_bf16(aq, bk, s[n], 0, 0, 0);
            }
        }

        const int qrow = q0 + w * 16 + ((l >> 4) << 2);
        const int kcol = k0 + (l & 15);
        float p[4][4];
#pragma unroll
        for (int n = 0; n < 4; ++n) {
#pragma unroll
            for (int r = 0; r < 4; ++r) {
                int key = kcol + n * 16;
                int q = qrow + r;
                int dd = q - key; if (dd < 0) dd = -dd;
                bool banned = (key < 0) || (key >= L) || (dd > W);
                p[n][r] = banned ? -1e30f : s[n][r] * 0.125f;
            }
        }
        float mx[4];
#pragma unroll
        for (int r = 0; r < 4; ++r)
            mx[r] = fmaxf(fmaxf(p[0][r], p[1][r]), fmaxf(p[2][r], p[3][r]));
#pragma unroll
        for (int off = 8; off >= 1; off >>= 1)
#pragma unroll
            for (int r = 0; r < 4; ++r)
                mx[r] = fmaxf(mx[r], __shfl_xor(mx[r], off));

        float sc[4], mn[4];
#pragma unroll
        for (int r = 0; r < 4; ++r) {
            mn[r] = fmaxf(mrow[r], mx[r]);
            sc[r] = __expf(mrow[r] - mn[r]);
            mrow[r] = mn[r];
        }
        float rs[4] = {0.f, 0.f, 0.f, 0.f};
#pragma unroll
        for (int n = 0; n < 4; ++n)
#pragma unroll
            for (int r = 0; r < 4; ++r) {
                float pv = __expf(p[n][r] - mn[r]);
                p[n][r] = pv;
                rs[r] += pv;
            }
#pragma unroll
        for (int off = 8; off >= 1; off >>= 1)
#pragma unroll
            for (int r = 0; r < 4; ++r)
                rs[r] += __shfl_xor(rs[r], off);
#pragma unroll
        for (int r = 0; r < 4; ++r)
            lrow[r] = lrow[r] * sc[r] + rs[r];
#pragma unroll
        for (int n = 0; n < 4; ++n)
#pragma unroll
            for (int r = 0; r < 4; ++r)
                o[n][r] *= sc[r];

#pragma unroll
        for (int n = 0; n < 4; ++n) {
            int col = n * 16 + (l & 15);
            int cb = col >> 3, ci = col & 7;
#pragma unroll
            for (int r = 0; r < 4; ++r) {
                int rp = w * 16 + ((l >> 4) << 2) + r;
                Ps[rp * 64 + ((cb ^ (rp & 7)) << 3) + ci] = f2b(p[n][r]);
            }
        }
#pragma unroll
        for (int kk = 0; kk < 2; ++kk) {
            const int aro = w * 16 + (l & 15);
            bf16x8 ap = *(const bf16x8*)&Ps[aro * 64 + (((kk * 4 + (l >> 4)) ^ (aro & 7)) << 3)];
#pragma unroll
            for (int n = 0; n < 4; ++n) {
                const int bro = n * 16 + (l & 15);
                bf16x8 bv = *(const bf16x8*)&Vs[bro * 64 + (((kk * 4 + (l >> 4)) ^ (bro & 7)) << 3)];
                o[n] = __builtin_amdgcn_mfma_f32_16x16x32_bf16(ap, bv, o[n], 0, 0, 0);
            }
        }
    }

#pragma unroll
    for (int n = 0; n < 4; ++n) {
        int col = h * 64 + n * 16 + (l & 15);
#pragma unroll
        for (int r = 0; r < 4; ++r) {
            int q = q0 + w * 16 + ((l >> 4) << 2) + r;
            ctx[(long)q * 768 + col] = f2b(o[n][r] / lrow[r]);
        }
    }
}

// ---------------- residual + 2-slice split-K reduce + bias + LayerNorm ----------------
// out = LN(A + (parts0 + parts1 + pbias)) * w + b ; f32 out + optional bf16 out
__global__ __launch_bounds__(256) void ln_res2(
    const float* __restrict__ A, const float* __restrict__ parts,
    const float* __restrict__ pbias,
    const float* __restrict__ w, const float* __restrict__ bb,
    float* __restrict__ outf, unsigned short* __restrict__ outb)
{
    const int D = 768;
    const long PS = (long)4096 * 768;
    const int row = blockIdx.x;
    const int t = threadIdx.x;
    const long base = (long)row * D;
    float xs[3];
#pragma unroll
    for (int i = 0; i < 3; ++i) {
        int c = t + i * 256;
        xs[i] = A[base + c] + pbias[c] + parts[base + c] + parts[PS + base + c];
    }
    float s = xs[0] + xs[1] + xs[2];
    float ss = xs[0] * xs[0] + xs[1] * xs[1] + xs[2] * xs[2];
#pragma unroll
    for (int off = 32; off >= 1; off >>= 1) {
        s += __shfl_xor(s, off);
        ss += __shfl_xor(ss, off);
    }
    __shared__ float sm[8];
    if ((t & 63) == 0) { sm[t >> 6] = s; sm[(t >> 6) + 4] = ss; }
    __syncthreads();
    s = sm[0] + sm[1] + sm[2] + sm[3];
    ss = sm[4] + sm[5] + sm[6] + sm[7];
    float mu = s * (1.0f / 768.0f);
    float var = ss * (1.0f / 768.0f) - mu * mu;
    float rstd = rsqrtf(var + 1e-5f);
#pragma unroll
    for (int i = 0; i < 3; ++i) {
        int c = t + i * 256;
        float y = (xs[i] - mu) * rstd * w[c] + bb[c];
        outf[base + c] = y;
        if (outb) outb[base + c] = f2b(y);
    }
}

extern "C" void kernel_launch(void* const* d_in, const int* in_sizes, int n_in,
                              void* d_out, int out_size, void* d_ws, size_t ws_size,
                              hipStream_t stream) {
    const float* x   = (const float*)d_in[0];
    const float* ipw = (const float*)d_in[1];
    const float* ipb = (const float*)d_in[2];
    const float* ow  = (const float*)d_in[3];
    const float* ob  = (const float*)d_in[4];
    const float* l1w = (const float*)d_in[5];
    const float* l1b = (const float*)d_in[6];
    const float* l2w = (const float*)d_in[7];
    const float* l2b = (const float*)d_in[8];
    const float* fw1 = (const float*)d_in[9];
    const float* fb1 = (const float*)d_in[10];
    const float* fw2 = (const float*)d_in[11];
    const float* fb2 = (const float*)d_in[12];
    const int*   win = (const int*)d_in[13];

    const int L = 4096, D = 768, TD = 2304, FF = 3072;
    char* p = (char*)d_ws;
    unsigned short* xb   = (unsigned short*)p; p += (size_t)L * D * 2;
    unsigned short* wqkv = (unsigned short*)p; p += (size_t)TD * D * 2;
    unsigned short* wout = (unsigned short*)p; p += (size_t)D * D * 2;
    unsigned short* wf1  = (unsigned short*)p; p += (size_t)FF * D * 2;
    unsigned short* wf2  = (unsigned short*)p; p += (size_t)FF * D * 2;
    unsigned short* ctxb = (unsigned short*)p; p += (size_t)L * D * 2;   // ctx, then LN1 bf16 out
    float* parts         = (float*)p;          p += (size_t)2 * L * D * 4; // 2 split-K slices
    float* hf            = (float*)p;          p += (size_t)L * D * 4;
    unsigned short* big  = (unsigned short*)p; p += (size_t)L * FF * 2;  // qkv bf16, then gelu-act
    unsigned short* qkvb = big;
    unsigned short* gb   = big;
    unsigned short* hb   = ctxb;

    // fused f32->bf16 converts (2555904 float4s)
    cvt_all<<<9984, 256, 0, stream>>>(x, xb, ipw, wqkv, ow, wout, fw1, wf1, fw2, wf2);

    // qkv = x @ in_proj_w^T + b -> bf16 [L, 2304]   (576 blocks, 12 iters)
    gemm_nt_p<0><<<dim3(TD / 128, L / 128, 1), 256, 0, stream>>>(xb, wqkv, ipb, nullptr, qkvb, L, TD, D);
    // banded attention -> ctx bf16 [L, 768]
    attn_local<<<dim3(L / 64, 12), 256, 0, stream>>>(qkvb, ctxb, win);
    // attn_out partials: ctx @ out_w^T (384 blocks, split-K=2, 6 iters)
    gemm_nt_p<3><<<dim3(D / 128, L / 128, 2), 256, 0, stream>>>(ctxb, wout, nullptr, parts, nullptr, L, D, D);
    // h = LN(x + partials + ob) -> f32 + bf16
    ln_res2<<<L, 256, 0, stream>>>(x, parts, ob, l1w, l1b, hf, hb);
    // g = gelu(h @ ff_w1^T + b1) -> bf16 [L, 3072]  (768 blocks, 12 iters)
    gemm_nt_p<2><<<dim3(FF / 128, L / 128, 1), 256, 0, stream>>>(hb, wf1, fb1, nullptr, gb, L, FF, D);
    // ff partials: g @ ff_w2^T (384 blocks, split-K=2, 24 iters)
    gemm_nt_p<3><<<dim3(D / 128, L / 128, 2), 256, 0, stream>>>(gb, wf2, nullptr, parts, nullptr, L, D, FF);
    // out = LN(h + partials + fb2) -> f32
    ln_res2<<<L, 256, 0, stream>>>(hf, parts, fb2, l2w, l2b, (float*)d_out, nullptr);
}